// Round 8
// baseline (372.248 us; speedup 1.0000x reference)
//
#include <hip/hip_runtime.h>
#include <hip/hip_bf16.h>
#include <hip/hip_fp16.h>

// GAT 2-layer forward. N=50000, E=800000 (+N self loops).
// L1: 128 -> 4x64 concat 256, ReLU.  L2: 256 -> 128, ReLU.
// R1: fused CSR softmax+aggregate.  R2: bf16 MFMA hi/lo split GEMMs.
// R3: fp16 h; full-N GEMM blocks.   R4: parallel 3-pass scan.
// R5: att_dots fused into GEMM epilogue.  R6: 4 nodes/256-thd agg block.
// R7: agg temporal channel-split (grid.y=2 halves the gather working set per
//     cohort -> better per-XCD L2 hit); prep_kernel fuses 2 memsets + split
//     + 2 pack_w (5 dispatches -> 1).

#define NEG_SLOPE 0.2f

typedef __attribute__((ext_vector_type(8))) short s16x8;   // 8 x 16-bit = 4 VGPRs
typedef __attribute__((ext_vector_type(4))) float f32x4;

__device__ inline unsigned short f2bf(float f) {            // RNE f32 -> bf16
    unsigned int u = __float_as_uint(f);
    u += 0x7fff + ((u >> 16) & 1);
    return (unsigned short)(u >> 16);
}
__device__ inline float bf2f(unsigned short h) {
    return __uint_as_float(((unsigned int)h) << 16);
}

// 16B load of 8 fp16 -> 8 fp32
__device__ inline void loadH8(float* v, const __half* p) {
    union { s16x8 raw; __half2 h2[4]; } u;
    u.raw = *(const s16x8*)p;
#pragma unroll
    for (int i = 0; i < 4; ++i) {
        float2 f = __half22float2(u.h2[i]);
        v[2 * i] = f.x;
        v[2 * i + 1] = f.y;
    }
}

// ---------------- CSR build ----------------

__global__ void count_kernel(const int* __restrict__ ei, int E, int N, int* __restrict__ cnt) {
    int e = blockIdx.x * blockDim.x + threadIdx.x;
    int Etot = E + N;
    if (e >= Etot) return;
    int d = (e < E) ? ei[E + e] : (e - E);
    atomicAdd(&cnt[d], 1);
}

__global__ void scan_blocks(const int* __restrict__ cnt, int* __restrict__ row_start,
                            int* __restrict__ bsum, int N) {
    __shared__ int sm[256];
    int t = threadIdx.x;
    int i = blockIdx.x * 256 + t;
    int c = (i < N) ? cnt[i] : 0;
    sm[t] = c;
    __syncthreads();
    for (int off = 1; off < 256; off <<= 1) {
        int v = (t >= off) ? sm[t - off] : 0;
        __syncthreads();
        sm[t] += v;
        __syncthreads();
    }
    if (i < N) row_start[i] = sm[t] - c;
    if (t == 255) bsum[blockIdx.x] = sm[255];
}

__global__ void scan_bsums(int* __restrict__ bsum, int* __restrict__ row_start, int nb, int N) {
    __shared__ int sm[256];
    int t = threadIdx.x;
    int v = (t < nb) ? bsum[t] : 0;
    sm[t] = v;
    __syncthreads();
    for (int off = 1; off < 256; off <<= 1) {
        int u = (t >= off) ? sm[t - off] : 0;
        __syncthreads();
        sm[t] += u;
        __syncthreads();
    }
    if (t < nb) bsum[t] = sm[t] - v;
    if (t == 255) row_start[N] = sm[255];
}

__global__ void scan_add(int* __restrict__ row_start, const int* __restrict__ bsum,
                         int* __restrict__ cursor, int N) {
    int i = blockIdx.x * 256 + threadIdx.x;
    if (i >= N) return;
    int v = row_start[i] + bsum[blockIdx.x];
    row_start[i] = v;
    cursor[i] = v;
}

__global__ void fill_kernel(const int* __restrict__ ei, int E, int N, int* __restrict__ cursor,
                            int* __restrict__ csr_src) {
    int e = blockIdx.x * blockDim.x + threadIdx.x;
    int Etot = E + N;
    if (e >= Etot) return;
    int s, d;
    if (e < E) { s = ei[e]; d = ei[E + e]; } else { s = e - E; d = s; }
    int pos = atomicAdd(&cursor[d], 1);
    csr_src[pos] = s;
}

// ---------------- fused prep: zero cnt/as2/ad2, split x, pack W1, pack W2 ----

__device__ inline void pack_w_elem(const float* __restrict__ W, unsigned short* __restrict__ bph,
                                   unsigned short* __restrict__ bpl, int K, int N, int tid) {
    int k = tid / N, n = tid - k * N;
    int ks = k >> 5, k5 = k & 31, quad = k5 >> 3, j = k5 & 7;
    int ct = n >> 4;
    int lane = quad * 16 + (n & 15);
    size_t idx = ((size_t)(ct * (K >> 5) + ks) * 64 + lane) * 8 + j;
    float w = W[tid];
    unsigned short h = f2bf(w);
    bph[idx] = h;
    bpl[idx] = f2bf(w - bf2f(h));
}

__global__ __launch_bounds__(256) void prep_kernel(
        const float* __restrict__ x, unsigned short* __restrict__ xh,
        unsigned short* __restrict__ xl, int nx,
        const float* __restrict__ W1, unsigned short* __restrict__ bp1h,
        unsigned short* __restrict__ bp1l,
        const float* __restrict__ W2, unsigned short* __restrict__ bp2h,
        unsigned short* __restrict__ bp2l,
        int* __restrict__ cnt, float* __restrict__ as2, float* __restrict__ ad2, int N) {
    int tid = blockIdx.x * blockDim.x + threadIdx.x;
    if (tid < nx) {
        float v = x[tid];
        unsigned short h = f2bf(v);
        xh[tid] = h;
        xl[tid] = f2bf(v - bf2f(h));
    }
    if (tid < N) {
        cnt[tid] = 0;
        as2[tid] = 0.f;
        ad2[tid] = 0.f;
    }
    if (tid < 128 * 256) pack_w_elem(W1, bp1h, bp1l, 128, 256, tid);
    if (tid < 256 * 128) pack_w_elem(W2, bp2h, bp2l, 256, 128, tid);
}

// ---------------- split-precision bf16 MFMA GEMM + fused attention dots ----

template<int K, int NN, int H, bool ATOMIC>
__global__ __launch_bounds__(256) void mfma_gemm(int M,
        const unsigned short* __restrict__ Ah, const unsigned short* __restrict__ Al,
        const unsigned short* __restrict__ Bph, const unsigned short* __restrict__ Bpl,
        const float* __restrict__ att_s, const float* __restrict__ att_d,
        float* __restrict__ as_, float* __restrict__ ad_,
        __half* __restrict__ Hout) {
    constexpr int KS = K >> 5;
    constexpr int CW = NN / 64;            // waves across columns
    constexpr int RW = 4 / CW;             // row-wave groups per block
    constexpr int C = NN / H;              // channels per head
    const int lane = threadIdx.x & 63;
    const int w = threadIdx.x >> 6;
    const int wr = w / CW;
    const int wc = w % CW;
    const int quad = lane >> 4;
    const int r16 = lane & 15;
    const int mBase = blockIdx.x * (RW * 32) + wr * 32;
    const int nBase = wc * 64;
    const int head = nBase / C;

    f32x4 acc[2][4];
#pragma unroll
    for (int rt = 0; rt < 2; ++rt)
#pragma unroll
        for (int ct = 0; ct < 4; ++ct) acc[rt][ct] = (f32x4){0.f, 0.f, 0.f, 0.f};

#pragma unroll
    for (int ks = 0; ks < KS; ++ks) {
        s16x8 ahf[2], alf[2];
#pragma unroll
        for (int rt = 0; rt < 2; ++rt) {
            int row = mBase + rt * 16 + r16;
            if (row < M) {
                size_t off = (size_t)row * K + ks * 32 + quad * 8;
                ahf[rt] = *(const s16x8*)(Ah + off);
                alf[rt] = *(const s16x8*)(Al + off);
            } else {
                ahf[rt] = (s16x8){0,0,0,0,0,0,0,0};
                alf[rt] = (s16x8){0,0,0,0,0,0,0,0};
            }
        }
        s16x8 bhf[4], blf[4];
#pragma unroll
        for (int ct = 0; ct < 4; ++ct) {
            int ctg = (nBase >> 4) + ct;
            size_t off = ((size_t)(ctg * KS + ks) * 64 + lane) * 8;
            bhf[ct] = *(const s16x8*)(Bph + off);
            blf[ct] = *(const s16x8*)(Bpl + off);
        }
#pragma unroll
        for (int rt = 0; rt < 2; ++rt)
#pragma unroll
            for (int ct = 0; ct < 4; ++ct) {
                acc[rt][ct] = __builtin_amdgcn_mfma_f32_16x16x32_bf16(ahf[rt], bhf[ct], acc[rt][ct], 0, 0, 0);
                acc[rt][ct] = __builtin_amdgcn_mfma_f32_16x16x32_bf16(ahf[rt], blf[ct], acc[rt][ct], 0, 0, 0);
                acc[rt][ct] = __builtin_amdgcn_mfma_f32_16x16x32_bf16(alf[rt], bhf[ct], acc[rt][ct], 0, 0, 0);
            }
    }

    // ---- store h (fp16); C/D layout: lane l reg r -> row=(l>>4)*4+r, col=l&15
#pragma unroll
    for (int rt = 0; rt < 2; ++rt)
#pragma unroll
        for (int ct = 0; ct < 4; ++ct) {
            int row0 = mBase + rt * 16 + quad * 4;
            int col = nBase + ct * 16 + r16;
#pragma unroll
            for (int r = 0; r < 4; ++r) {
                int row = row0 + r;
                if (row < M) Hout[(size_t)row * NN + col] = __float2half(acc[rt][ct][r]);
            }
        }

    // ---- fused attention dots
    float attS[4], attD[4];
#pragma unroll
    for (int ct = 0; ct < 4; ++ct) {
        int cc = (nBase % C) + ct * 16 + r16;   // channel within head
        attS[ct] = att_s[head * C + cc];
        attD[ct] = att_d[head * C + cc];
    }
#pragma unroll
    for (int rt = 0; rt < 2; ++rt)
#pragma unroll
        for (int r = 0; r < 4; ++r) {
            float ps = 0.f, pd = 0.f;
#pragma unroll
            for (int ct = 0; ct < 4; ++ct) {
                ps += acc[rt][ct][r] * attS[ct];
                pd += acc[rt][ct][r] * attD[ct];
            }
#pragma unroll
            for (int off = 1; off < 16; off <<= 1) {
                ps += __shfl_xor(ps, off);
                pd += __shfl_xor(pd, off);
            }
            int row = mBase + rt * 16 + quad * 4 + r;
            if (r16 == 0 && row < M) {
                if (ATOMIC) {
                    atomicAdd(&as_[row * H + head], ps);
                    atomicAdd(&ad_[row * H + head], pd);
                } else {
                    as_[row * H + head] = ps;
                    ad_[row * H + head] = pd;
                }
            }
        }
}

// ---------------- fused CSR softmax + aggregate (fp16 gather) ----------------
// grid = (N/4, 2): blockIdx.y selects channel half (temporal L2 working-set
// split -- x-major dispatch runs the y=0 cohort first). 256-thd block = 4
// independent waves, wave w handles node blk*4+w; each wave iterates ALL of
// its node's edges but gathers only CHW channels.

__device__ inline float edge_w(float a) {
    float e = a > 0.f ? a : NEG_SLOPE * a;
    return __expf(e);
}

template<int U, int HC, int H, int GRP>
__device__ inline void agg_step(int p, const int* __restrict__ csr_src,
                                const __half* __restrict__ h,
                                const float* __restrict__ as_, float adv,
                                int c0, int head, float* acc, float& den) {
    int srcv[U];
#pragma unroll
    for (int u = 0; u < U; ++u) srcv[u] = csr_src[p + u * GRP];
    float f[U][8];
#pragma unroll
    for (int u = 0; u < U; ++u) loadH8(f[u], h + (size_t)srcv[u] * HC + c0);
    float wv[U];
#pragma unroll
    for (int u = 0; u < U; ++u) wv[u] = edge_w(as_[srcv[u] * H + head] + adv);
#pragma unroll
    for (int u = 0; u < U; ++u) den += wv[u];
#pragma unroll
    for (int u = 0; u < U; ++u)
#pragma unroll
        for (int i = 0; i < 8; ++i) acc[i] += wv[u] * f[u][i];
}

template<int HC, int CHW, int H, bool BF16OUT>
__global__ __launch_bounds__(256) void fused_agg(int N,
                                                 const int* __restrict__ row_start,
                                                 const int* __restrict__ csr_src,
                                                 const __half* __restrict__ h,
                                                 const float* __restrict__ as_,
                                                 const float* __restrict__ ad_,
                                                 const float* __restrict__ bias,
                                                 float* __restrict__ out,
                                                 unsigned short* __restrict__ outh,
                                                 unsigned short* __restrict__ outl) {
    constexpr int LPE = CHW / 8;         // lanes per edge (16 or 8)
    constexpr int GRP = 64 / LPE;        // concurrent edges per wave (4 or 8)
    constexpr int C = HC / H;
    const int n = blockIdx.x * 4 + (threadIdx.x >> 6);
    if (n >= N) return;
    const int lane = threadIdx.x & 63;
    const int g = lane / LPE;
    const int lq = lane % LPE;
    const int c0 = blockIdx.y * CHW + lq * 8;
    const int head = c0 / C;
    const int s0 = row_start[n], s1 = row_start[n + 1];
    const float adv = ad_[n * H + head];
    float acc[8] = {};
    float den = 0.f;
    int p = s0 + g;
    for (; p + 3 * GRP < s1; p += 4 * GRP)
        agg_step<4, HC, H, GRP>(p, csr_src, h, as_, adv, c0, head, acc, den);
    for (; p < s1; p += GRP)
        agg_step<1, HC, H, GRP>(p, csr_src, h, as_, adv, c0, head, acc, den);
#pragma unroll
    for (int off = LPE; off < 64; off <<= 1) {
        den += __shfl_xor(den, off);
#pragma unroll
        for (int i = 0; i < 8; ++i) acc[i] += __shfl_xor(acc[i], off);
    }
    if (g == 0) {
        float dinv = 1.0f / (den + 1e-16f);
        float o[8];
#pragma unroll
        for (int i = 0; i < 8; ++i) {
            float v = acc[i] * dinv + bias[c0 + i];
            o[i] = v > 0.f ? v : 0.f;
        }
        if (BF16OUT) {
            s16x8 hb, lb;
#pragma unroll
            for (int i = 0; i < 8; ++i) {
                unsigned short hh = f2bf(o[i]);
                hb[i] = (short)hh;
                lb[i] = (short)f2bf(o[i] - bf2f(hh));
            }
            *(s16x8*)(outh + (size_t)n * HC + c0) = hb;
            *(s16x8*)(outl + (size_t)n * HC + c0) = lb;
        } else {
            float4 v0 = make_float4(o[0], o[1], o[2], o[3]);
            float4 v1 = make_float4(o[4], o[5], o[6], o[7]);
            *(float4*)(out + (size_t)n * HC + c0) = v0;
            *(float4*)(out + (size_t)n * HC + c0 + 4) = v1;
        }
    }
}

extern "C" void kernel_launch(void* const* d_in, const int* in_sizes, int n_in,
                              void* d_out, int out_size, void* d_ws, size_t ws_size,
                              hipStream_t stream) {
    const float* x      = (const float*)d_in[0];
    const int*   ei     = (const int*)d_in[1];
    const float* W1     = (const float*)d_in[2];
    const float* att_s1 = (const float*)d_in[3];
    const float* att_d1 = (const float*)d_in[4];
    const float* b1     = (const float*)d_in[5];
    const float* W2     = (const float*)d_in[6];
    const float* att_s2 = (const float*)d_in[7];
    const float* att_d2 = (const float*)d_in[8];
    const float* b2     = (const float*)d_in[9];
    float* out = (float*)d_out;

    const int N_ = in_sizes[0] / 128;   // 50000
    const int E_ = in_sizes[1] / 2;     // 800000
    const int Etot = E_ + N_;           // 850000

    // workspace layout
    __half* h1 = (__half*)d_ws;                              // N*256 fp16 (also h2)
    unsigned short* x2h = (unsigned short*)(h1 + (size_t)N_ * 256);  // N*256 bf16
    unsigned short* x2l = x2h + (size_t)N_ * 256;                    // N*256 bf16
    unsigned short* xh = x2h;                                // N*128 bf16 (overlay)
    unsigned short* xl = x2l;                                // N*128 bf16 (overlay)
    unsigned short* bp1h = x2l + (size_t)N_ * 256;           // 32768
    unsigned short* bp1l = bp1h + 32768;
    unsigned short* bp2h = bp1l + 32768;
    unsigned short* bp2l = bp2h + 32768;
    float* as1 = (float*)(bp2l + 32768);                     // N*4
    float* ad1 = as1 + (size_t)N_ * 4;                       // N*4
    float* as2 = ad1 + (size_t)N_ * 4;                       // N
    float* ad2 = as2 + N_;                                   // N
    int* cnt       = (int*)(ad2 + N_);                       // N
    int* row_start = cnt + N_;                               // N+1
    int* cursor    = row_start + (N_ + 1);                   // N
    int* bsum      = cursor + N_;                            // 256
    int* csr_src   = bsum + 256;                             // Etot

    int eb = (Etot + 255) / 256;
    int nb = (N_ + 255) / 256;          // 196
    int nx = N_ * 128;

    prep_kernel<<<(nx + 255) / 256, 256, 0, stream>>>(
        x, xh, xl, nx, W1, bp1h, bp1l, W2, bp2h, bp2l, cnt, as2, ad2, N_);
    count_kernel<<<eb, 256, 0, stream>>>(ei, E_, N_, cnt);
    scan_blocks<<<nb, 256, 0, stream>>>(cnt, row_start, bsum, N_);
    scan_bsums<<<1, 256, 0, stream>>>(bsum, row_start, nb, N_);
    scan_add<<<nb, 256, 0, stream>>>(row_start, bsum, cursor, N_);
    fill_kernel<<<eb, 256, 0, stream>>>(ei, E_, N_, cursor, csr_src);

    // ---- layer 1: 128 -> 4x64 ----
    mfma_gemm<128, 256, 4, false><<<(N_ + 31) / 32, 256, 0, stream>>>(
        N_, xh, xl, bp1h, bp1l, att_s1, att_d1, as1, ad1, h1);
    fused_agg<256, 128, 4, true><<<dim3((N_ + 3) / 4, 2), 256, 0, stream>>>(
        N_, row_start, csr_src, h1, as1, ad1, b1, nullptr, x2h, x2l);

    // ---- layer 2: 256 -> 1x128 ----
    __half* h2 = h1;  // reuse
    mfma_gemm<256, 128, 1, true><<<(N_ + 63) / 64, 256, 0, stream>>>(
        N_, x2h, x2l, bp2h, bp2l, att_s2, att_d2, as2, ad2, h2);
    fused_agg<128, 64, 1, false><<<dim3((N_ + 3) / 4, 2), 256, 0, stream>>>(
        N_, row_start, csr_src, h2, as2, ad2, b2, out, nullptr, nullptr);

    (void)n_in; (void)out_size; (void)ws_size;
}

// Round 9
// 331.910 us; speedup vs baseline: 1.1215x; 1.1215x over previous
//
#include <hip/hip_runtime.h>
#include <hip/hip_bf16.h>
#include <hip/hip_fp16.h>

// GAT 2-layer forward. N=50000, E=800000 (+N self loops).
// L1: 128 -> 4x64 concat 256, ReLU.  L2: 256 -> 128, ReLU.
// R1: fused CSR softmax+aggregate.  R2-R8: GEMMs via fp16 MFMA (single
// product -- fp16 products are exact in fp32 accum; input quantization
// ~2^-11 rel, measured headroom 3.6x). fp16 h gather (per-CU VMEM-issue
// floor ~10B/cyc/CU). R4: parallel scan. R5: att_dots in GEMM epilogue.
// R6: 4 nodes/256-thd agg block. R7 channel-split REVERTED (VALU duplication
// cost > L2 win). prep fuses memsets + x->fp16 + W packs.

#define NEG_SLOPE 0.2f

typedef __attribute__((ext_vector_type(8))) _Float16 f16x8;  // 8 fp16 = 4 VGPRs
typedef __attribute__((ext_vector_type(8))) short s16x8;
typedef __attribute__((ext_vector_type(4))) float f32x4;

// 16B load of 8 fp16 -> 8 fp32
__device__ inline void loadH8(float* v, const __half* p) {
    union { s16x8 raw; __half2 h2[4]; } u;
    u.raw = *(const s16x8*)p;
#pragma unroll
    for (int i = 0; i < 4; ++i) {
        float2 f = __half22float2(u.h2[i]);
        v[2 * i] = f.x;
        v[2 * i + 1] = f.y;
    }
}

// ---------------- CSR build ----------------

__global__ void count_kernel(const int* __restrict__ ei, int E, int N, int* __restrict__ cnt) {
    int e = blockIdx.x * blockDim.x + threadIdx.x;
    int Etot = E + N;
    if (e >= Etot) return;
    int d = (e < E) ? ei[E + e] : (e - E);
    atomicAdd(&cnt[d], 1);
}

__global__ void scan_blocks(const int* __restrict__ cnt, int* __restrict__ row_start,
                            int* __restrict__ bsum, int N) {
    __shared__ int sm[256];
    int t = threadIdx.x;
    int i = blockIdx.x * 256 + t;
    int c = (i < N) ? cnt[i] : 0;
    sm[t] = c;
    __syncthreads();
    for (int off = 1; off < 256; off <<= 1) {
        int v = (t >= off) ? sm[t - off] : 0;
        __syncthreads();
        sm[t] += v;
        __syncthreads();
    }
    if (i < N) row_start[i] = sm[t] - c;
    if (t == 255) bsum[blockIdx.x] = sm[255];
}

__global__ void scan_bsums(int* __restrict__ bsum, int* __restrict__ row_start, int nb, int N) {
    __shared__ int sm[256];
    int t = threadIdx.x;
    int v = (t < nb) ? bsum[t] : 0;
    sm[t] = v;
    __syncthreads();
    for (int off = 1; off < 256; off <<= 1) {
        int u = (t >= off) ? sm[t - off] : 0;
        __syncthreads();
        sm[t] += u;
        __syncthreads();
    }
    if (t < nb) bsum[t] = sm[t] - v;
    if (t == 255) row_start[N] = sm[255];
}

__global__ void scan_add(int* __restrict__ row_start, const int* __restrict__ bsum,
                         int* __restrict__ cursor, int N) {
    int i = blockIdx.x * 256 + threadIdx.x;
    if (i >= N) return;
    int v = row_start[i] + bsum[blockIdx.x];
    row_start[i] = v;
    cursor[i] = v;
}

__global__ void fill_kernel(const int* __restrict__ ei, int E, int N, int* __restrict__ cursor,
                            int* __restrict__ csr_src) {
    int e = blockIdx.x * blockDim.x + threadIdx.x;
    int Etot = E + N;
    if (e >= Etot) return;
    int s, d;
    if (e < E) { s = ei[e]; d = ei[E + e]; } else { s = e - E; d = s; }
    int pos = atomicAdd(&cursor[d], 1);
    csr_src[pos] = s;
}

// ---------------- fused prep: zero cnt/as2/ad2, x->fp16, pack W1, pack W2 ----
// B-frag (16x16x32): lane l holds B[k0 + (l>>4)*8 + j][n0 + (l&15)], j=0..7.

__device__ inline void pack_w_elem(const float* __restrict__ W, __half* __restrict__ bp,
                                   int K, int N, int tid) {
    int k = tid / N, n = tid - k * N;
    int ks = k >> 5, k5 = k & 31, quad = k5 >> 3, j = k5 & 7;
    int ct = n >> 4;
    int lane = quad * 16 + (n & 15);
    size_t idx = ((size_t)(ct * (K >> 5) + ks) * 64 + lane) * 8 + j;
    bp[idx] = __float2half(W[tid]);
}

__global__ __launch_bounds__(256) void prep_kernel(
        const float* __restrict__ x, __half* __restrict__ xf, int nx,
        const float* __restrict__ W1, __half* __restrict__ bp1,
        const float* __restrict__ W2, __half* __restrict__ bp2,
        int* __restrict__ cnt, float* __restrict__ as2, float* __restrict__ ad2, int N) {
    int tid = blockIdx.x * blockDim.x + threadIdx.x;
    if (tid < nx) xf[tid] = __float2half(x[tid]);
    if (tid < N) {
        cnt[tid] = 0;
        as2[tid] = 0.f;
        ad2[tid] = 0.f;
    }
    if (tid < 128 * 256) pack_w_elem(W1, bp1, 128, 256, tid);
    if (tid < 256 * 128) pack_w_elem(W2, bp2, 256, 128, tid);
}

// ---------------- fp16 MFMA GEMM + fused attention dots ----------------
// One block covers all NN columns. Epilogue computes a_s/a_d from fp32 acc.

template<int K, int NN, int H, bool ATOMIC>
__global__ __launch_bounds__(256) void mfma_gemm(int M,
        const __half* __restrict__ A, const __half* __restrict__ Bp,
        const float* __restrict__ att_s, const float* __restrict__ att_d,
        float* __restrict__ as_, float* __restrict__ ad_,
        __half* __restrict__ Hout) {
    constexpr int KS = K >> 5;
    constexpr int CW = NN / 64;            // waves across columns
    constexpr int RW = 4 / CW;             // row-wave groups per block
    constexpr int C = NN / H;              // channels per head
    const int lane = threadIdx.x & 63;
    const int w = threadIdx.x >> 6;
    const int wr = w / CW;
    const int wc = w % CW;
    const int quad = lane >> 4;
    const int r16 = lane & 15;
    const int mBase = blockIdx.x * (RW * 32) + wr * 32;
    const int nBase = wc * 64;
    const int head = nBase / C;

    f32x4 acc[2][4];
#pragma unroll
    for (int rt = 0; rt < 2; ++rt)
#pragma unroll
        for (int ct = 0; ct < 4; ++ct) acc[rt][ct] = (f32x4){0.f, 0.f, 0.f, 0.f};

#pragma unroll
    for (int ks = 0; ks < KS; ++ks) {
        f16x8 af[2];
#pragma unroll
        for (int rt = 0; rt < 2; ++rt) {
            int row = mBase + rt * 16 + r16;
            if (row < M) {
                size_t off = (size_t)row * K + ks * 32 + quad * 8;
                af[rt] = *(const f16x8*)(A + off);
            } else {
                af[rt] = (f16x8){0,0,0,0,0,0,0,0};
            }
        }
        f16x8 bf[4];
#pragma unroll
        for (int ct = 0; ct < 4; ++ct) {
            int ctg = (nBase >> 4) + ct;
            size_t off = ((size_t)(ctg * KS + ks) * 64 + lane) * 8;
            bf[ct] = *(const f16x8*)(Bp + off);
        }
#pragma unroll
        for (int rt = 0; rt < 2; ++rt)
#pragma unroll
            for (int ct = 0; ct < 4; ++ct)
                acc[rt][ct] = __builtin_amdgcn_mfma_f32_16x16x32_f16(af[rt], bf[ct], acc[rt][ct], 0, 0, 0);
    }

    // ---- store h (fp16); C/D layout: lane l reg r -> row=(l>>4)*4+r, col=l&15
#pragma unroll
    for (int rt = 0; rt < 2; ++rt)
#pragma unroll
        for (int ct = 0; ct < 4; ++ct) {
            int row0 = mBase + rt * 16 + quad * 4;
            int col = nBase + ct * 16 + r16;
#pragma unroll
            for (int r = 0; r < 4; ++r) {
                int row = row0 + r;
                if (row < M) Hout[(size_t)row * NN + col] = __float2half(acc[rt][ct][r]);
            }
        }

    // ---- fused attention dots
    float attS[4], attD[4];
#pragma unroll
    for (int ct = 0; ct < 4; ++ct) {
        int cc = (nBase % C) + ct * 16 + r16;   // channel within head
        attS[ct] = att_s[head * C + cc];
        attD[ct] = att_d[head * C + cc];
    }
#pragma unroll
    for (int rt = 0; rt < 2; ++rt)
#pragma unroll
        for (int r = 0; r < 4; ++r) {
            float ps = 0.f, pd = 0.f;
#pragma unroll
            for (int ct = 0; ct < 4; ++ct) {
                ps += acc[rt][ct][r] * attS[ct];
                pd += acc[rt][ct][r] * attD[ct];
            }
#pragma unroll
            for (int off = 1; off < 16; off <<= 1) {
                ps += __shfl_xor(ps, off);
                pd += __shfl_xor(pd, off);
            }
            int row = mBase + rt * 16 + quad * 4 + r;
            if (r16 == 0 && row < M) {
                if (ATOMIC) {
                    atomicAdd(&as_[row * H + head], ps);
                    atomicAdd(&ad_[row * H + head], pd);
                } else {
                    as_[row * H + head] = ps;
                    ad_[row * H + head] = pd;
                }
            }
        }
}

// ---------------- fused CSR softmax + aggregate (fp16 gather) ----------------
// 256-thread block = 4 independent waves, wave w handles node blk*4+w.

__device__ inline float edge_w(float a) {
    float e = a > 0.f ? a : NEG_SLOPE * a;
    return __expf(e);
}

template<int U, int HC, int H, int GRP>
__device__ inline void agg_step(int p, const int* __restrict__ csr_src,
                                const __half* __restrict__ h,
                                const float* __restrict__ as_, float adv,
                                int c0, int head, float* acc, float& den) {
    int srcv[U];
#pragma unroll
    for (int u = 0; u < U; ++u) srcv[u] = csr_src[p + u * GRP];
    float f[U][8];
#pragma unroll
    for (int u = 0; u < U; ++u) loadH8(f[u], h + (size_t)srcv[u] * HC + c0);
    float wv[U];
#pragma unroll
    for (int u = 0; u < U; ++u) wv[u] = edge_w(as_[srcv[u] * H + head] + adv);
#pragma unroll
    for (int u = 0; u < U; ++u) den += wv[u];
#pragma unroll
    for (int u = 0; u < U; ++u)
#pragma unroll
        for (int i = 0; i < 8; ++i) acc[i] += wv[u] * f[u][i];
}

template<int HC, int H, bool F16OUT>
__global__ __launch_bounds__(256) void fused_agg(int N,
                                                 const int* __restrict__ row_start,
                                                 const int* __restrict__ csr_src,
                                                 const __half* __restrict__ h,
                                                 const float* __restrict__ as_,
                                                 const float* __restrict__ ad_,
                                                 const float* __restrict__ bias,
                                                 float* __restrict__ out,
                                                 __half* __restrict__ outh) {
    constexpr int LPE = HC / 8;          // lanes per edge (32 or 16)
    constexpr int GRP = 64 / LPE;        // concurrent edges per wave (2 or 4)
    constexpr int C = HC / H;
    const int n = blockIdx.x * 4 + (threadIdx.x >> 6);
    if (n >= N) return;
    const int lane = threadIdx.x & 63;
    const int g = lane / LPE;
    const int lq = lane % LPE;
    const int c0 = lq * 8;
    const int head = c0 / C;
    const int s0 = row_start[n], s1 = row_start[n + 1];
    const float adv = ad_[n * H + head];
    float acc[8] = {};
    float den = 0.f;
    int p = s0 + g;
    for (; p + 3 * GRP < s1; p += 4 * GRP)
        agg_step<4, HC, H, GRP>(p, csr_src, h, as_, adv, c0, head, acc, den);
    for (; p < s1; p += GRP)
        agg_step<1, HC, H, GRP>(p, csr_src, h, as_, adv, c0, head, acc, den);
#pragma unroll
    for (int off = LPE; off < 64; off <<= 1) {
        den += __shfl_xor(den, off);
#pragma unroll
        for (int i = 0; i < 8; ++i) acc[i] += __shfl_xor(acc[i], off);
    }
    if (g == 0) {
        float dinv = 1.0f / (den + 1e-16f);
        float o[8];
#pragma unroll
        for (int i = 0; i < 8; ++i) {
            float v = acc[i] * dinv + bias[c0 + i];
            o[i] = v > 0.f ? v : 0.f;
        }
        if (F16OUT) {
            union { s16x8 raw; __half hv[8]; } u;
#pragma unroll
            for (int i = 0; i < 8; ++i) u.hv[i] = __float2half(o[i]);
            *(s16x8*)(outh + (size_t)n * HC + c0) = u.raw;
        } else {
            float4 v0 = make_float4(o[0], o[1], o[2], o[3]);
            float4 v1 = make_float4(o[4], o[5], o[6], o[7]);
            *(float4*)(out + (size_t)n * HC + c0) = v0;
            *(float4*)(out + (size_t)n * HC + c0 + 4) = v1;
        }
    }
}

extern "C" void kernel_launch(void* const* d_in, const int* in_sizes, int n_in,
                              void* d_out, int out_size, void* d_ws, size_t ws_size,
                              hipStream_t stream) {
    const float* x      = (const float*)d_in[0];
    const int*   ei     = (const int*)d_in[1];
    const float* W1     = (const float*)d_in[2];
    const float* att_s1 = (const float*)d_in[3];
    const float* att_d1 = (const float*)d_in[4];
    const float* b1     = (const float*)d_in[5];
    const float* W2     = (const float*)d_in[6];
    const float* att_s2 = (const float*)d_in[7];
    const float* att_d2 = (const float*)d_in[8];
    const float* b2     = (const float*)d_in[9];
    float* out = (float*)d_out;

    const int N_ = in_sizes[0] / 128;   // 50000
    const int E_ = in_sizes[1] / 2;     // 800000
    const int Etot = E_ + N_;           // 850000

    // workspace layout
    __half* h1 = (__half*)d_ws;                              // N*256 fp16 (also h2)
    __half* x2 = h1 + (size_t)N_ * 256;                      // N*256 fp16
    __half* xf = x2;                                         // N*128 fp16 (overlay:
                                                             // xf dead before agg1 writes x2)
    __half* bp1 = x2 + (size_t)N_ * 256;                     // 32768 fp16
    __half* bp2 = bp1 + 32768;                               // 32768 fp16
    float* as1 = (float*)(bp2 + 32768);                      // N*4
    float* ad1 = as1 + (size_t)N_ * 4;                       // N*4
    float* as2 = ad1 + (size_t)N_ * 4;                       // N
    float* ad2 = as2 + N_;                                   // N
    int* cnt       = (int*)(ad2 + N_);                       // N
    int* row_start = cnt + N_;                               // N+1
    int* cursor    = row_start + (N_ + 1);                   // N
    int* bsum      = cursor + N_;                            // 256
    int* csr_src   = bsum + 256;                             // Etot

    int eb = (Etot + 255) / 256;
    int nb = (N_ + 255) / 256;          // 196
    int nx = N_ * 128;

    prep_kernel<<<(nx + 255) / 256, 256, 0, stream>>>(
        x, xf, nx, W1, bp1, W2, bp2, cnt, as2, ad2, N_);
    count_kernel<<<eb, 256, 0, stream>>>(ei, E_, N_, cnt);
    scan_blocks<<<nb, 256, 0, stream>>>(cnt, row_start, bsum, N_);
    scan_bsums<<<1, 256, 0, stream>>>(bsum, row_start, nb, N_);
    scan_add<<<nb, 256, 0, stream>>>(row_start, bsum, cursor, N_);
    fill_kernel<<<eb, 256, 0, stream>>>(ei, E_, N_, cursor, csr_src);

    // ---- layer 1: 128 -> 4x64 ----
    mfma_gemm<128, 256, 4, false><<<(N_ + 31) / 32, 256, 0, stream>>>(
        N_, xf, bp1, att_s1, att_d1, as1, ad1, h1);
    fused_agg<256, 4, true><<<(N_ + 3) / 4, 256, 0, stream>>>(
        N_, row_start, csr_src, h1, as1, ad1, b1, nullptr, x2);

    // ---- layer 2: 256 -> 1x128 ----
    __half* h2 = h1;  // reuse
    mfma_gemm<256, 128, 1, true><<<(N_ + 63) / 64, 256, 0, stream>>>(
        N_, x2, bp2, att_s2, att_d2, as2, ad2, h2);
    fused_agg<128, 1, false><<<(N_ + 3) / 4, 256, 0, stream>>>(
        N_, row_start, csr_src, h2, as2, ad2, b2, out, nullptr);

    (void)n_in; (void)out_size; (void)ws_size;
}